// Round 5
// baseline (156.146 us; speedup 1.0000x reference)
//
#include <hip/hip_runtime.h>
#include <hip/hip_bf16.h>
#include <math.h>

#define T_DIM 2048
#define B_DIM 16
#define M_DIM 512
#define H_DIM 256
#define KC 512
#define K_DIM 512
#define CHUNK 64
#define NCHUNK 32
#define BK 32
#define NTILE 16            // K / BK

typedef unsigned short ushort_t;
typedef __attribute__((ext_vector_type(8))) short short8;
typedef __attribute__((ext_vector_type(8))) unsigned short ushort8;
typedef __attribute__((ext_vector_type(4))) float f32x4;

// ---- workspace layout (float offsets); total 17301504 floats = 69.2 MB ----
#define WS_CARRY 0            // 262144 floats
#define WS_WB_BF 262144       // 262144 ushorts (tiled k-major)
#define WS_WC_BF 393216       // 262144 ushorts (tiled k-major)
#define WS_BU    524288       // 16777216 ushorts: Bu natural [n][col] bf16
#define WS_HT    8912896      // 16777216 ushorts: H tiled k-major bf16

__device__ inline ushort_t f2bf(float f) {
    __hip_bfloat16 h = __float2bfloat16(f);
    return *reinterpret_cast<ushort_t*>(&h);
}
__device__ inline float bf2f(ushort_t u) {
    union { unsigned int i; float f; } v;
    v.i = ((unsigned int)u) << 16;
    return v.f;
}

// bf16 weights pre-tiled: idx = ((blk*16 + t)*512 + ks*128 + row)*8 + e
//   <-> W[j = blk*128+row][k = t*32 + ks*8 + e]
__global__ void prep_w(const float* __restrict__ B_re, const float* __restrict__ B_im,
                       const float* __restrict__ gamma_log,
                       const float* __restrict__ C_re, const float* __restrict__ C_im,
                       ushort_t* __restrict__ wb, ushort_t* __restrict__ wc) {
    int idx = blockIdx.x * blockDim.x + threadIdx.x;  // 0..262143
    int e    = idx & 7;
    int slot = (idx >> 3) & 511;
    int row  = slot & 127;
    int ks   = slot >> 7;
    int t    = (idx >> 12) & 15;
    int blk  = idx >> 16;
    int j = blk * 128 + row;
    int k = t * 32 + ks * 8 + e;
    float v;
    if (j < 256) v = expf(gamma_log[j])       * B_re[j * 512 + k];
    else         v = expf(gamma_log[j - 256]) * B_im[(j - 256) * 512 + k];
    wb[idx] = f2bf(v);
    float w;
    if (k < 256) w =  C_re[j * 256 + k];
    else         w = -C_im[j * 256 + (k - 256)];
    wc[idx] = f2bf(w);
}

// NT GEMM via MFMA bf16, double-buffered 2-phase, k-major conflict-free LDS.
// A_TILED=1: A is bf16 pre-tiled (same layout as weights) -> global_load_lds.
// A_TILED=0: A is fp32 natural -> reg-staged (load early, cvt+ds_write late).
// OUT_BF16=1: bf16 natural output; else fp32 output + D[col]*X epilogue.
template <int A_TILED, int OUT_BF16>
__global__ __launch_bounds__(256) void gemm_mfma(
    const void* __restrict__ Aptr, const ushort_t* __restrict__ Wt,
    void* __restrict__ Cv, const float* __restrict__ Dv,
    const float* __restrict__ X) {
    __shared__ ushort_t Asl[2][4096];   // 8KB per buf: chunk = ks*128+row, 8 ushorts
    __shared__ ushort_t Bsl[2][4096];
    const int tid = threadIdx.x;
    const int rb = blockIdx.x;          // row-panel 0..255
    const int nb = blockIdx.y;          // col-panel 0..3
    const int bm = rb << 7, bn = nb << 7;
    const int lane = tid & 63, wid = tid >> 6;
    const int wr  = (wid >> 1) << 6;
    const int wcc = (wid & 1) << 6;
    const int l16 = lane & 15, ksl = lane >> 4;
    const int c0 = tid, c1 = tid + 256;
    // reg-staging map (A_TILED=0): thread -> row=tid>>1, ks={aks,aks+1}
    const int arow = tid >> 1;
    const int aks  = (tid & 1) << 1;
    const int as0  = (aks * 128 + arow) * 8;
    const int as1  = as0 + 1024;

    const float*    Af = (const float*)Aptr;
    const ushort_t* At = (const ushort_t*)Aptr;

    f32x4 acc[4][4] = {};
    float4 pva0, pva1, pvb0, pvb1;

    auto loadA = [&](int t) {
        if constexpr (!A_TILED) {
            const float* p = Af + (size_t)(bm + arow) * K_DIM + t * BK + aks * 8;
            pva0 = *(const float4*)(p);
            pva1 = *(const float4*)(p + 4);
            pvb0 = *(const float4*)(p + 8);
            pvb1 = *(const float4*)(p + 12);
        }
    };
    auto stage = [&](int t, int buf) {
        if constexpr (A_TILED) {
            size_t ab = ((size_t)(rb * NTILE + t)) * 4096;
            __builtin_amdgcn_global_load_lds(
                (const __attribute__((address_space(1))) void*)(At + ab + c0 * 8),
                (__attribute__((address_space(3))) void*)(&Asl[buf][c0 * 8]), 16, 0, 0);
            __builtin_amdgcn_global_load_lds(
                (const __attribute__((address_space(1))) void*)(At + ab + c1 * 8),
                (__attribute__((address_space(3))) void*)(&Asl[buf][c1 * 8]), 16, 0, 0);
        }
        size_t bb = ((size_t)(nb * NTILE + t)) * 4096;
        __builtin_amdgcn_global_load_lds(
            (const __attribute__((address_space(1))) void*)(Wt + bb + c0 * 8),
            (__attribute__((address_space(3))) void*)(&Bsl[buf][c0 * 8]), 16, 0, 0);
        __builtin_amdgcn_global_load_lds(
            (const __attribute__((address_space(1))) void*)(Wt + bb + c1 * 8),
            (__attribute__((address_space(3))) void*)(&Bsl[buf][c1 * 8]), 16, 0, 0);
    };
    auto writeA = [&](int buf) {
        if constexpr (!A_TILED) {
            ushort8 u0, u1;
            u0[0] = f2bf(pva0.x); u0[1] = f2bf(pva0.y); u0[2] = f2bf(pva0.z); u0[3] = f2bf(pva0.w);
            u0[4] = f2bf(pva1.x); u0[5] = f2bf(pva1.y); u0[6] = f2bf(pva1.z); u0[7] = f2bf(pva1.w);
            u1[0] = f2bf(pvb0.x); u1[1] = f2bf(pvb0.y); u1[2] = f2bf(pvb0.z); u1[3] = f2bf(pvb0.w);
            u1[4] = f2bf(pvb1.x); u1[5] = f2bf(pvb1.y); u1[6] = f2bf(pvb1.z); u1[7] = f2bf(pvb1.w);
            *(ushort8*)(&Asl[buf][as0]) = u0;
            *(ushort8*)(&Asl[buf][as1]) = u1;
        }
    };

    loadA(0);
    stage(0, 0);
    writeA(0);
    __syncthreads();

    int cur = 0;
    for (int t = 0; t < NTILE; ++t) {
        const int nxt = cur ^ 1;
        if (t + 1 < NTILE) { loadA(t + 1); stage(t + 1, nxt); }
        short8 afr[4], bfr[4];
#pragma unroll
        for (int m = 0; m < 4; ++m)
            afr[m] = *(const short8*)(&Asl[cur][(ksl * 128 + wr + m * 16 + l16) * 8]);
#pragma unroll
        for (int n = 0; n < 4; ++n)
            bfr[n] = *(const short8*)(&Bsl[cur][(ksl * 128 + wcc + n * 16 + l16) * 8]);
        __builtin_amdgcn_s_setprio(1);
#pragma unroll
        for (int m = 0; m < 4; ++m)
#pragma unroll
            for (int n = 0; n < 4; ++n)
                acc[m][n] = __builtin_amdgcn_mfma_f32_16x16x32_bf16(
                    afr[m], bfr[n], acc[m][n], 0, 0, 0);
        __builtin_amdgcn_s_setprio(0);
        if (t + 1 < NTILE) writeA(nxt);
        __syncthreads();
        cur = nxt;
    }

    // epilogue: C/D layout col=lane&15, row=(lane>>4)*4+reg
    const int fr = (lane >> 4) << 2;
#pragma unroll
    for (int m = 0; m < 4; ++m) {
#pragma unroll
        for (int n = 0; n < 4; ++n) {
#pragma unroll
            for (int r = 0; r < 4; ++r) {
                int row = bm + wr + m * 16 + fr + r;
                int col = bn + wcc + n * 16 + l16;
                size_t o = (size_t)row * 512 + col;
                float v = acc[m][n][r];
                if constexpr (OUT_BF16) {
                    ((ushort_t*)Cv)[o] = f2bf(v);
                } else {
                    ((float*)Cv)[o] = v + Dv[col] * X[o];
                }
            }
        }
    }
}

// Pass A: per (chunk c, batch b, state h): local scan, zero init, store end value.
__global__ __launch_bounds__(256) void scan_local(const float* __restrict__ nu_log,
        const float* __restrict__ theta_log, float* __restrict__ ws) {
    const int c = blockIdx.x >> 4;
    const int b = blockIdx.x & 15;
    const int h = threadIdx.x;
    const float nu = expf(nu_log[h]);
    const float th = expf(theta_log[h]);
    const float r  = expf(-nu);
    const float lr = r * cosf(th), li = r * sinf(th);
    const ushort_t* Bu = (const ushort_t*)(ws + WS_BU);
    float hr = 0.f, hi = 0.f;
    const int t0 = c * CHUNK;
    for (int l = 0; l < CHUNK; ++l) {
        size_t idx = ((size_t)(t0 + l) * B_DIM + b) * KC + h;
        float br = bf2f(Bu[idx]), bi = bf2f(Bu[idx + 256]);
        float nr = fmaf(lr, hr, fmaf(-li, hi, br));
        float ni = fmaf(lr, hi, fmaf(li, hr, bi));
        hr = nr; hi = ni;
    }
    size_t cidx = ((size_t)(c * B_DIM + b)) * KC + h;
    ws[WS_CARRY + cidx]       = hr;
    ws[WS_CARRY + cidx + 256] = hi;
}

// Pass B: sequential over 32 chunk aggregates; h_final planar re/im to out tail.
__global__ __launch_bounds__(256) void scan_carry(const float* __restrict__ nu_log,
        const float* __restrict__ theta_log, float* __restrict__ ws,
        const float* __restrict__ h_re, const float* __restrict__ h_im,
        float* __restrict__ out, int out_size) {
    const int b = blockIdx.x;
    const int h = threadIdx.x;
    const float nu = expf(nu_log[h]);
    const float th = expf(theta_log[h]);
    const float rL  = expf(-64.f * nu);
    const float thL = 64.f * th;
    const float Lr = rL * cosf(thL), Li = rL * sinf(thL);
    float cr = h_re[b * H_DIM + h], ci = h_im[b * H_DIM + h];
    for (int c = 0; c < NCHUNK; ++c) {
        size_t cidx = ((size_t)(c * B_DIM + b)) * KC + h;
        float sr = ws[WS_CARRY + cidx], si = ws[WS_CARRY + cidx + 256];
        ws[WS_CARRY + cidx]       = cr;
        ws[WS_CARRY + cidx + 256] = ci;
        float nr = fmaf(Lr, cr, fmaf(-Li, ci, sr));
        float ni = fmaf(Lr, ci, fmaf(Li, cr, si));
        cr = nr; ci = ni;
    }
    const size_t base = (size_t)T_DIM * B_DIM * M_DIM;
    const size_t idx  = (size_t)b * H_DIM + h;
    size_t ore = base + idx;
    size_t oim = base + (size_t)B_DIM * H_DIM + idx;
    if (ore < (size_t)out_size) out[ore] = cr;
    if (oim < (size_t)out_size) out[oim] = ci;
}

// Pass C: replay each chunk from carry-in; write H in TILED k-major bf16 layout
// (ready for GEMM2's global_load_lds A staging).
__global__ __launch_bounds__(256) void scan_apply(const float* __restrict__ nu_log,
        const float* __restrict__ theta_log, float* __restrict__ ws) {
    const int c = blockIdx.x >> 4;
    const int b = blockIdx.x & 15;
    const int h = threadIdx.x;
    const float nu = expf(nu_log[h]);
    const float th = expf(theta_log[h]);
    const float rr = expf(-nu);
    const float lr = rr * cosf(th), li = rr * sinf(th);
    const ushort_t* Bu = (const ushort_t*)(ws + WS_BU);
    ushort_t* Ht = (ushort_t*)(ws + WS_HT);
    size_t cidx = ((size_t)(c * B_DIM + b)) * KC + h;
    float hr = ws[WS_CARRY + cidx], hi = ws[WS_CARRY + cidx + 256];
    // tiled coords for col_re = h and col_im = h+256
    const int t_re = h >> 5;            // 0..7 (im: +8)
    const int ks_e = (h >> 3) & 3;
    const int e_   = h & 7;
    const int t0 = c * CHUNK;
    for (int l = 0; l < CHUNK; ++l) {
        int n = (t0 + l) * B_DIM + b;
        size_t idx = (size_t)n * KC + h;
        float br = bf2f(Bu[idx]), bi = bf2f(Bu[idx + 256]);
        float nr = fmaf(lr, hr, fmaf(-li, hi, br));
        float ni = fmaf(lr, hi, fmaf(li, hr, bi));
        hr = nr; hi = ni;
        int rbk = n >> 7, rr_ = n & 127;
        size_t ire = (((size_t)(rbk * NTILE + t_re)) * 512 + ks_e * 128 + rr_) * 8 + e_;
        size_t iim = (((size_t)(rbk * NTILE + t_re + 8)) * 512 + ks_e * 128 + rr_) * 8 + e_;
        Ht[ire] = f2bf(hr);
        Ht[iim] = f2bf(hi);
    }
}

extern "C" void kernel_launch(void* const* d_in, const int* in_sizes, int n_in,
                              void* d_out, int out_size, void* d_ws, size_t ws_size,
                              hipStream_t stream) {
    const float* inputs    = (const float*)d_in[0];
    const float* h_re      = (const float*)d_in[1];
    const float* h_im      = (const float*)d_in[2];
    const float* nu_log    = (const float*)d_in[3];
    const float* theta_log = (const float*)d_in[4];
    const float* gamma_log = (const float*)d_in[5];
    const float* B_re      = (const float*)d_in[6];
    const float* B_im      = (const float*)d_in[7];
    const float* C_re      = (const float*)d_in[8];
    const float* C_im      = (const float*)d_in[9];
    const float* Dv        = (const float*)d_in[10];
    float* out = (float*)d_out;
    float* ws  = (float*)d_ws;
    ushort_t* wb = (ushort_t*)(ws + WS_WB_BF);
    ushort_t* wc = (ushort_t*)(ws + WS_WC_BF);
    ushort_t* bu = (ushort_t*)(ws + WS_BU);
    ushort_t* ht = (ushort_t*)(ws + WS_HT);

    prep_w<<<1024, 256, 0, stream>>>(B_re, B_im, gamma_log, C_re, C_im, wb, wc);

    // GEMM1: Bu[n][j] = X[n][:] . Wb[j][:]  (fp32 A reg-staged, bf16 natural out)
    gemm_mfma<0, 1><<<dim3(256, 4), 256, 0, stream>>>(inputs, wb, (void*)bu,
                                                      nullptr, nullptr);

    scan_local<<<NCHUNK * B_DIM, 256, 0, stream>>>(nu_log, theta_log, ws);
    scan_carry<<<B_DIM, 256, 0, stream>>>(nu_log, theta_log, ws, h_re, h_im,
                                          out, out_size);
    scan_apply<<<NCHUNK * B_DIM, 256, 0, stream>>>(nu_log, theta_log, ws);

    // GEMM2: Y[n][m] = H[n][:] . Wc[m][:] + D[m]*X[n][m]  (tiled bf16 A via
    // global_load_lds, fp32 out + epilogue)
    gemm_mfma<1, 0><<<dim3(256, 4), 256, 0, stream>>>(ht, wc, (void*)out,
                                                      Dv, inputs);
}

// Round 6
// 134.337 us; speedup vs baseline: 1.1623x; 1.1623x over previous
//
#include <hip/hip_runtime.h>
#include <hip/hip_bf16.h>
#include <math.h>

#define T_DIM 2048
#define B_DIM 16
#define M_DIM 512
#define H_DIM 256
#define KC 512
#define K_DIM 512
#define CHUNK 64
#define NCHUNK 32
#define BK 32
#define NTILE 16            // K / BK

typedef unsigned short ushort_t;
typedef __attribute__((ext_vector_type(8))) short short8;
typedef __attribute__((ext_vector_type(8))) unsigned short ushort8;
typedef __attribute__((ext_vector_type(4))) float f32x4;

// ---- workspace layout (float offsets); total ~69.2 MB ----
#define WS_CARRY 0            // 262144 floats
#define WS_WB_BF 262144       // 262144 ushorts (tiled k-major)
#define WS_WC_BF 393216       // 262144 ushorts (tiled k-major)
#define WS_BU    524288       // 16777216 ushorts: Bu natural [n][col] bf16
#define WS_HT    8912896      // 16777216 ushorts: H tiled k-major bf16

__device__ inline ushort_t f2bf(float f) {
    __hip_bfloat16 h = __float2bfloat16(f);
    return *reinterpret_cast<ushort_t*>(&h);
}
__device__ inline float bf2f(ushort_t u) {
    union { unsigned int i; float f; } v;
    v.i = ((unsigned int)u) << 16;
    return v.f;
}

// bf16 weights pre-tiled: idx = ((blk*16 + t)*512 + ks*128 + row)*8 + e
//   <-> W[j = blk*128+row][k = t*32 + ks*8 + e]
__global__ void prep_w(const float* __restrict__ B_re, const float* __restrict__ B_im,
                       const float* __restrict__ gamma_log,
                       const float* __restrict__ C_re, const float* __restrict__ C_im,
                       ushort_t* __restrict__ wb, ushort_t* __restrict__ wc) {
    int idx = blockIdx.x * blockDim.x + threadIdx.x;  // 0..262143
    int e    = idx & 7;
    int slot = (idx >> 3) & 511;
    int row  = slot & 127;
    int ks   = slot >> 7;
    int t    = (idx >> 12) & 15;
    int blk  = idx >> 16;
    int j = blk * 128 + row;
    int k = t * 32 + ks * 8 + e;
    float v;
    if (j < 256) v = expf(gamma_log[j])       * B_re[j * 512 + k];
    else         v = expf(gamma_log[j - 256]) * B_im[(j - 256) * 512 + k];
    wb[idx] = f2bf(v);
    float w;
    if (k < 256) w =  C_re[j * 256 + k];
    else         w = -C_im[j * 256 + (k - 256)];
    wc[idx] = f2bf(w);
}

// NT GEMM via MFMA bf16, double-buffered 2-phase (R4-proven structure:
// unroll 2 -> static buffer indices, no setprio, stage-before-loadA order).
// A_TILED=1: A bf16 pre-tiled -> global_load_lds both operands.
// A_TILED=0: A fp32 natural -> reg-staged (load early, cvt+ds_write late).
// OUT_BF16=1: bf16 natural output; else fp32 output + D[col]*X epilogue.
template <int A_TILED, int OUT_BF16>
__global__ __launch_bounds__(256) void gemm_mfma(
    const void* __restrict__ Aptr, const ushort_t* __restrict__ Wt,
    void* __restrict__ Cv, const float* __restrict__ Dv,
    const float* __restrict__ X) {
    __shared__ ushort_t Asl[2][4096];   // 8KB/buf: slot = ks*128+row, 8 ushorts
    __shared__ ushort_t Bsl[2][4096];
    const int tid = threadIdx.x;
    const int rb = blockIdx.x;          // row-panel 0..255
    const int nb = blockIdx.y;          // col-panel 0..3
    const int bm = rb << 7, bn = nb << 7;
    const int lane = tid & 63, wid = tid >> 6;
    const int wr  = (wid >> 1) << 6;
    const int wcc = (wid & 1) << 6;
    const int l16 = lane & 15, ksl = lane >> 4;
    const int c0 = tid, c1 = tid + 256;
    // reg-staging map (A_TILED=0): thread -> row=tid>>1, ks={aks,aks+1}
    const int arow = tid >> 1;
    const int aks  = (tid & 1) << 1;
    const int as0  = (aks * 128 + arow) * 8;
    const int as1  = as0 + 1024;

    const float*    Af = (const float*)Aptr;
    const ushort_t* At = (const ushort_t*)Aptr;

    f32x4 acc[4][4] = {};
    float4 pva0, pva1, pvb0, pvb1;

    auto stage = [&](int t, int buf) {
        if constexpr (A_TILED) {
            size_t ab = ((size_t)(rb * NTILE + t)) * 4096;
            __builtin_amdgcn_global_load_lds(
                (const __attribute__((address_space(1))) void*)(At + ab + c0 * 8),
                (__attribute__((address_space(3))) void*)(&Asl[buf][c0 * 8]), 16, 0, 0);
            __builtin_amdgcn_global_load_lds(
                (const __attribute__((address_space(1))) void*)(At + ab + c1 * 8),
                (__attribute__((address_space(3))) void*)(&Asl[buf][c1 * 8]), 16, 0, 0);
        }
        size_t bb = ((size_t)(nb * NTILE + t)) * 4096;
        __builtin_amdgcn_global_load_lds(
            (const __attribute__((address_space(1))) void*)(Wt + bb + c0 * 8),
            (__attribute__((address_space(3))) void*)(&Bsl[buf][c0 * 8]), 16, 0, 0);
        __builtin_amdgcn_global_load_lds(
            (const __attribute__((address_space(1))) void*)(Wt + bb + c1 * 8),
            (__attribute__((address_space(3))) void*)(&Bsl[buf][c1 * 8]), 16, 0, 0);
    };
    auto loadA = [&](int t) {
        if constexpr (!A_TILED) {
            const float* p = Af + (size_t)(bm + arow) * K_DIM + t * BK + aks * 8;
            pva0 = *(const float4*)(p);
            pva1 = *(const float4*)(p + 4);
            pvb0 = *(const float4*)(p + 8);
            pvb1 = *(const float4*)(p + 12);
        }
    };
    auto writeA = [&](int buf) {
        if constexpr (!A_TILED) {
            ushort8 u0, u1;
            u0[0] = f2bf(pva0.x); u0[1] = f2bf(pva0.y); u0[2] = f2bf(pva0.z); u0[3] = f2bf(pva0.w);
            u0[4] = f2bf(pva1.x); u0[5] = f2bf(pva1.y); u0[6] = f2bf(pva1.z); u0[7] = f2bf(pva1.w);
            u1[0] = f2bf(pvb0.x); u1[1] = f2bf(pvb0.y); u1[2] = f2bf(pvb0.z); u1[3] = f2bf(pvb0.w);
            u1[4] = f2bf(pvb1.x); u1[5] = f2bf(pvb1.y); u1[6] = f2bf(pvb1.z); u1[7] = f2bf(pvb1.w);
            *(ushort8*)(&Asl[buf][as0]) = u0;
            *(ushort8*)(&Asl[buf][as1]) = u1;
        }
    };

    stage(0, 0);
    loadA(0);
    writeA(0);
    __syncthreads();

    int cur = 0;
#pragma unroll 2
    for (int t = 0; t < NTILE; ++t) {
        const int nxt = cur ^ 1;
        if (t + 1 < NTILE) { stage(t + 1, nxt); loadA(t + 1); }
        short8 afr[4], bfr[4];
#pragma unroll
        for (int m = 0; m < 4; ++m)
            afr[m] = *(const short8*)(&Asl[cur][(ksl * 128 + wr + m * 16 + l16) * 8]);
#pragma unroll
        for (int n = 0; n < 4; ++n)
            bfr[n] = *(const short8*)(&Bsl[cur][(ksl * 128 + wcc + n * 16 + l16) * 8]);
#pragma unroll
        for (int m = 0; m < 4; ++m)
#pragma unroll
            for (int n = 0; n < 4; ++n)
                acc[m][n] = __builtin_amdgcn_mfma_f32_16x16x32_bf16(
                    afr[m], bfr[n], acc[m][n], 0, 0, 0);
        if (t + 1 < NTILE) writeA(nxt);
        __syncthreads();
        cur = nxt;
    }

    // epilogue: C/D layout col=lane&15, row=(lane>>4)*4+reg
    const int fr = (lane >> 4) << 2;
#pragma unroll
    for (int m = 0; m < 4; ++m) {
#pragma unroll
        for (int n = 0; n < 4; ++n) {
#pragma unroll
            for (int r = 0; r < 4; ++r) {
                int row = bm + wr + m * 16 + fr + r;
                int col = bn + wcc + n * 16 + l16;
                size_t o = (size_t)row * 512 + col;
                float v = acc[m][n][r];
                if constexpr (OUT_BF16) {
                    ((ushort_t*)Cv)[o] = f2bf(v);
                } else {
                    ((float*)Cv)[o] = v + Dv[col] * X[o];
                }
            }
        }
    }
}

// Pass A: per (chunk c, batch b): 128 threads, each owns h-pair {2i, 2i+1};
// packed uint (2x bf16) loads. Local scan, zero init, store end value.
__global__ __launch_bounds__(128) void scan_local(const float* __restrict__ nu_log,
        const float* __restrict__ theta_log, float* __restrict__ ws) {
    const int c = blockIdx.x >> 4;
    const int b = blockIdx.x & 15;
    const int i = threadIdx.x;          // 0..127
    const int h0 = 2 * i;
    float lr[2], li[2];
#pragma unroll
    for (int q = 0; q < 2; ++q) {
        float nu = expf(nu_log[h0 + q]);
        float th = expf(theta_log[h0 + q]);
        float r  = expf(-nu);
        lr[q] = r * cosf(th); li[q] = r * sinf(th);
    }
    const ushort_t* Bu = (const ushort_t*)(ws + WS_BU);
    float hr[2] = {0.f, 0.f}, hi[2] = {0.f, 0.f};
    const int t0 = c * CHUNK;
    for (int l = 0; l < CHUNK; ++l) {
        size_t base = ((size_t)(t0 + l) * B_DIM + b) * KC;
        unsigned int vre = *(const unsigned int*)(&Bu[base + h0]);
        unsigned int vim = *(const unsigned int*)(&Bu[base + 256 + h0]);
#pragma unroll
        for (int q = 0; q < 2; ++q) {
            float br = bf2f((ushort_t)(q ? (vre >> 16) : (vre & 0xffff)));
            float bi = bf2f((ushort_t)(q ? (vim >> 16) : (vim & 0xffff)));
            float nr = fmaf(lr[q], hr[q], fmaf(-li[q], hi[q], br));
            float ni = fmaf(lr[q], hi[q], fmaf(li[q], hr[q], bi));
            hr[q] = nr; hi[q] = ni;
        }
    }
    size_t cb = ((size_t)(c * B_DIM + b)) * KC;
    *(float2*)(&ws[WS_CARRY + cb + h0])       = make_float2(hr[0], hr[1]);
    *(float2*)(&ws[WS_CARRY + cb + 256 + h0]) = make_float2(hi[0], hi[1]);
}

// Pass B: sequential over 32 chunk aggregates; h_final planar re/im to out tail.
__global__ __launch_bounds__(256) void scan_carry(const float* __restrict__ nu_log,
        const float* __restrict__ theta_log, float* __restrict__ ws,
        const float* __restrict__ h_re, const float* __restrict__ h_im,
        float* __restrict__ out, int out_size) {
    const int b = blockIdx.x;
    const int h = threadIdx.x;
    const float nu = expf(nu_log[h]);
    const float th = expf(theta_log[h]);
    const float rL  = expf(-64.f * nu);
    const float thL = 64.f * th;
    const float Lr = rL * cosf(thL), Li = rL * sinf(thL);
    float cr = h_re[b * H_DIM + h], ci = h_im[b * H_DIM + h];
    for (int c = 0; c < NCHUNK; ++c) {
        size_t cidx = ((size_t)(c * B_DIM + b)) * KC + h;
        float sr = ws[WS_CARRY + cidx], si = ws[WS_CARRY + cidx + 256];
        ws[WS_CARRY + cidx]       = cr;
        ws[WS_CARRY + cidx + 256] = ci;
        float nr = fmaf(Lr, cr, fmaf(-Li, ci, sr));
        float ni = fmaf(Lr, ci, fmaf(Li, cr, si));
        cr = nr; ci = ni;
    }
    const size_t base = (size_t)T_DIM * B_DIM * M_DIM;
    const size_t idx  = (size_t)b * H_DIM + h;
    size_t ore = base + idx;
    size_t oim = base + (size_t)B_DIM * H_DIM + idx;
    if (ore < (size_t)out_size) out[ore] = cr;
    if (oim < (size_t)out_size) out[oim] = ci;
}

// Pass C: replay chunk from carry-in; write H TILED k-major bf16 (packed uint).
__global__ __launch_bounds__(128) void scan_apply(const float* __restrict__ nu_log,
        const float* __restrict__ theta_log, float* __restrict__ ws) {
    const int c = blockIdx.x >> 4;
    const int b = blockIdx.x & 15;
    const int i = threadIdx.x;          // 0..127
    const int h0 = 2 * i;
    float lr[2], li[2];
#pragma unroll
    for (int q = 0; q < 2; ++q) {
        float nu = expf(nu_log[h0 + q]);
        float th = expf(theta_log[h0 + q]);
        float r  = expf(-nu);
        lr[q] = r * cosf(th); li[q] = r * sinf(th);
    }
    const ushort_t* Bu = (const ushort_t*)(ws + WS_BU);
    ushort_t* Ht = (ushort_t*)(ws + WS_HT);
    size_t cb = ((size_t)(c * B_DIM + b)) * KC;
    float2 f2r = *(const float2*)(&ws[WS_CARRY + cb + h0]);
    float2 f2i = *(const float2*)(&ws[WS_CARRY + cb + 256 + h0]);
    float hr[2] = {f2r.x, f2r.y}, hi[2] = {f2i.x, f2i.y};
    // tiled coords for col_re = h0 (even, pair contiguous): e = h0&7
    const int t_re = h0 >> 5;
    const int ks_e = (h0 >> 3) & 3;
    const int e_   = h0 & 7;
    const int t0 = c * CHUNK;
    for (int l = 0; l < CHUNK; ++l) {
        int n = (t0 + l) * B_DIM + b;
        size_t base = (size_t)n * KC;
        unsigned int vre = *(const unsigned int*)(&Bu[base + h0]);
        unsigned int vim = *(const unsigned int*)(&Bu[base + 256 + h0]);
#pragma unroll
        for (int q = 0; q < 2; ++q) {
            float br = bf2f((ushort_t)(q ? (vre >> 16) : (vre & 0xffff)));
            float bi = bf2f((ushort_t)(q ? (vim >> 16) : (vim & 0xffff)));
            float nr = fmaf(lr[q], hr[q], fmaf(-li[q], hi[q], br));
            float ni = fmaf(lr[q], hi[q], fmaf(li[q], hr[q], bi));
            hr[q] = nr; hi[q] = ni;
        }
        int rbk = n >> 7, row = n & 127;
        size_t ire = (((size_t)(rbk * NTILE + t_re)) * 512 + ks_e * 128 + row) * 8 + e_;
        size_t iim = (((size_t)(rbk * NTILE + t_re + 8)) * 512 + ks_e * 128 + row) * 8 + e_;
        unsigned int pre = (unsigned int)f2bf(hr[0]) | ((unsigned int)f2bf(hr[1]) << 16);
        unsigned int pim = (unsigned int)f2bf(hi[0]) | ((unsigned int)f2bf(hi[1]) << 16);
        *(unsigned int*)(&Ht[ire]) = pre;
        *(unsigned int*)(&Ht[iim]) = pim;
    }
}

extern "C" void kernel_launch(void* const* d_in, const int* in_sizes, int n_in,
                              void* d_out, int out_size, void* d_ws, size_t ws_size,
                              hipStream_t stream) {
    const float* inputs    = (const float*)d_in[0];
    const float* h_re      = (const float*)d_in[1];
    const float* h_im      = (const float*)d_in[2];
    const float* nu_log    = (const float*)d_in[3];
    const float* theta_log = (const float*)d_in[4];
    const float* gamma_log = (const float*)d_in[5];
    const float* B_re      = (const float*)d_in[6];
    const float* B_im      = (const float*)d_in[7];
    const float* C_re      = (const float*)d_in[8];
    const float* C_im      = (const float*)d_in[9];
    const float* Dv        = (const float*)d_in[10];
    float* out = (float*)d_out;
    float* ws  = (float*)d_ws;
    ushort_t* wb = (ushort_t*)(ws + WS_WB_BF);
    ushort_t* wc = (ushort_t*)(ws + WS_WC_BF);
    ushort_t* bu = (ushort_t*)(ws + WS_BU);
    ushort_t* ht = (ushort_t*)(ws + WS_HT);

    prep_w<<<1024, 256, 0, stream>>>(B_re, B_im, gamma_log, C_re, C_im, wb, wc);

    // GEMM1: Bu[n][j] = X[n][:] . Wb[j][:]  (fp32 A reg-staged, bf16 natural out)
    gemm_mfma<0, 1><<<dim3(256, 4), 256, 0, stream>>>(inputs, wb, (void*)bu,
                                                      nullptr, nullptr);

    scan_local<<<NCHUNK * B_DIM, 128, 0, stream>>>(nu_log, theta_log, ws);
    scan_carry<<<B_DIM, 256, 0, stream>>>(nu_log, theta_log, ws, h_re, h_im,
                                          out, out_size);
    scan_apply<<<NCHUNK * B_DIM, 128, 0, stream>>>(nu_log, theta_log, ws);

    // GEMM2: Y[n][m] = H[n][:] . Wc[m][:] + D[m]*X[n][m]  (tiled bf16 A via
    // global_load_lds, fp32 out + epilogue)
    gemm_mfma<1, 0><<<dim3(256, 4), 256, 0, stream>>>(ht, wc, (void*)out,
                                                      Dv, inputs);
}